// Round 12
// baseline (115.982 us; speedup 1.0000x reference)
//
#include <hip/hip_runtime.h>

typedef unsigned short ushortT;
typedef short bf16x8 __attribute__((ext_vector_type(8)));
typedef float f32x4 __attribute__((ext_vector_type(4)));
#define MFMA __builtin_amdgcn_mfma_f32_16x16x32_bf16

#define B_ 16
#define L_ 512
#define N_ 64
#define D_ 256
#define Q_ 128

// ---- workspace byte offsets -----------------------------------------------
#define OFF_GRE  0u          // g_re [48 bc3][64 n][256 d] f32
#define OFF_GIM  3145728u    // g_im
#define OFF_KPAD 6291456u    // Kpad [128][256] f32, row = tau (no zero rows)
#define OFF_ABT  6422528u    // AbReh/AbRel/AbImh/AbIml 64x128 bf16 each
#define OFF_PT   6488064u    // P1h/P1l/P2h/P2l 128x64 bf16 each
#define OFF_BAR  6553600u    // 2 x u32 grid-barrier state (cnt, gen)

#define GRID_MAIN 768        // 3 blocks/CU x 256 CUs -> all co-resident
#define NB_B      512        // phase-B work units

__device__ __forceinline__ ushortT f2bf(float f) {
    unsigned u = __float_as_uint(f);
    return (ushortT)((u + 0x7FFFu + ((u >> 16) & 1u)) >> 16);   // RNE
}
__device__ __forceinline__ float bf2f(ushortT h) {
    return __uint_as_float(((unsigned)h) << 16);
}
__device__ __forceinline__ void split2(float f, ushortT& hi, ushortT& lo) {
    hi = f2bf(f); lo = f2bf(f - bf2f(hi));
}

// device-scope two-phase counter barrier; requires all blocks co-resident.
__device__ __forceinline__ void grid_barrier(unsigned* bar, unsigned nb) {
    __syncthreads();
    if (threadIdx.x == 0) {
        unsigned* cnt = bar;
        unsigned* gen = bar + 1;
        __threadfence();                              // release phase-A writes
        const unsigned g = atomicAdd(gen, 0u);        // read generation
        const unsigned old = atomicAdd(cnt, 1u);
        if (old == nb - 1u) {
            atomicExch(cnt, 0u);
            __threadfence();
            atomicAdd(gen, 1u);                       // release the barrier
        } else {
            while (atomicAdd(gen, 0u) == g)
                __builtin_amdgcn_s_sleep(8);
        }
        __threadfence();                              // acquire others' writes
    }
    __syncthreads();
}

// ---------------------------------------------------------------------------
// prep: blocks 0..127 -> Kpad row (tau=blk); 128..135 -> Ab & P tables;
//       block 136 -> zero the grid-barrier counters.
// ---------------------------------------------------------------------------
__global__ __launch_bounds__(256)
void prep_kernel(const float* __restrict__ Lre, const float* __restrict__ Lim,
                 const float* __restrict__ Bre, const float* __restrict__ Bim,
                 const float* __restrict__ Pre, const float* __restrict__ Pim,
                 const float* __restrict__ logdt, char* __restrict__ ws)
{
    const int blk = blockIdx.x, t = threadIdx.x;
    const float dt = expf(logdt[0]);

    if (blk < 128) {                          // ---- Kpad[tau][d]
        float* Kpad = (float*)(ws + OFF_KPAD);
        __shared__ float U[N_], V[N_];
        const int tau = blk, d = t;
        if (d < N_) {
            const float eL = expf(Lre[d]);
            const float wre = -eL * cosf(Lim[d]), wim = -eL * sinf(Lim[d]);
            const float er = expf(tau * dt * wre);
            float sn, cs; sincosf(tau * dt * wim, &sn, &cs);
            const float Ar = er * cs, Ai = er * sn;
            const float bdr = dt * Bre[d], bdi = dt * Bim[d];
            U[d] = bdr * Ar - bdi * Ai;
            V[d] = bdi * Ar + bdr * Ai;
        }
        __syncthreads();
        float acc = 0.f;
        #pragma unroll 8
        for (int n = 0; n < N_; ++n)
            acc = fmaf(Pre[n * D_ + d], U[n], fmaf(-Pim[n * D_ + d], V[n], acc));
        Kpad[tau * D_ + d] = acc;

    } else if (blk < 136) {                   // ---- Ab & P tables (8 blocks)
        ushortT* AbReh = (ushortT*)(ws + OFF_ABT);
        ushortT* AbRel = AbReh + 8192;
        ushortT* AbImh = AbReh + 16384;
        ushortT* AbIml = AbReh + 24576;
        ushortT* P1h = (ushortT*)(ws + OFF_PT);
        ushortT* P1l = P1h + 8192;
        ushortT* P2h = P1h + 16384;
        ushortT* P2l = P1h + 24576;
        const int g = blk - 128;
        const int n = t & 63, q = t >> 6;
        const float eL = expf(Lre[n]);
        const float xr = dt * (-eL * cosf(Lim[n]));
        const float xi = dt * (-eL * sinf(Lim[n]));
        #pragma unroll
        for (int jj = 0; jj < 4; ++jj) {      // Abar[n][j] = a^(127-j)
            const int j = g * 16 + q * 4 + jj;
            const float p = (float)(127 - j);
            const float er = expf(p * xr);
            float sn, cs; sincosf(p * xi, &sn, &cs);
            split2(er * cs, AbReh[n * Q_ + j], AbRel[n * Q_ + j]);
            split2(er * sn, AbImh[n * Q_ + j], AbIml[n * Q_ + j]);
        }
        #pragma unroll
        for (int ii = 0; ii < 4; ++ii) {      // P[i][n] from a^(i+1)
            const int i = g * 16 + q * 4 + ii;
            const float p = (float)(i + 1);
            const float er = expf(p * xr);
            float sn, cs; sincosf(p * xi, &sn, &cs);
            split2(er * cs,  P1h[i * N_ + n], P1l[i * N_ + n]);
            split2(-er * sn, P2h[i * N_ + n], P2l[i * N_ + n]);   // -Im
        }
    } else {                                  // ---- barrier init
        if (t < 2) ((unsigned*)(ws + OFF_BAR))[t] = 0u;
    }
}

// ---------------------------------------------------------------------------
// main (single dispatch):
//   phase A (768 blocks): g = Ab @ u per (bc3, dq16)   [verified gstage math]
//   grid barrier (all co-resident by construction)
//   phase B (512 blocks): h-combine -> W -> P@W GEMM -> FIR -> y  [verified]
// LDS overlay: A uses [0,8704); B uses ylds@0, Wl@16896, uS@35328, kSb@43520.
// ---------------------------------------------------------------------------
__global__ __launch_bounds__(256, 3)
void main_kernel(const float* __restrict__ u,
                 const float* __restrict__ Lre, const float* __restrict__ Lim,
                 const float* __restrict__ Bre, const float* __restrict__ Bim,
                 const float* __restrict__ Pre, const float* __restrict__ Pim,
                 const float* __restrict__ logdt, char* __restrict__ ws,
                 float* __restrict__ y)
{
    __shared__ __align__(16) char smem[51712];

    const int bid = blockIdx.x;
    const int t = threadIdx.x, l = t & 63, w = t >> 6;
    const float dt = expf(logdt[0]);

    // ================= phase A: g = Ab @ u ================================
    {
        ushortT* ldsH = (ushortT*)smem;               // [16][136]
        ushortT* ldsL = (ushortT*)(smem + 4352);
        const int bc3 = bid >> 4, dq = bid & 15;
        const int b = bc3 / 3, c = bc3 % 3;
        {
            const int dl = t & 15, j0 = t >> 4;
            const float* ug = u + ((size_t)(b * L_ + c * Q_) * D_) + dq * 16 + dl;
            #pragma unroll
            for (int p = 0; p < 8; ++p) {
                const int j = j0 + 16 * p;
                ushortT hh, ll;
                split2(ug[(size_t)j * D_], hh, ll);
                ldsH[dl * 136 + j] = hh; ldsL[dl * 136 + j] = ll;
            }
        }
        __syncthreads();

        const ushortT* AbReh = (const ushortT*)(ws + OFF_ABT);
        const ushortT* AbRel = AbReh + 8192;
        const ushortT* AbImh = AbReh + 16384;
        const ushortT* AbIml = AbReh + 24576;

        f32x4 gre = {}, gim = {};
        #pragma unroll
        for (int ks = 0; ks < 4; ++ks) {
            const int aoff = (16 * w + (l & 15)) * Q_ + 32 * ks + 8 * (l >> 4);
            const bf16x8 aRh = *(const bf16x8*)(AbReh + aoff);
            const bf16x8 aRl = *(const bf16x8*)(AbRel + aoff);
            const bf16x8 aIh = *(const bf16x8*)(AbImh + aoff);
            const bf16x8 aIl = *(const bf16x8*)(AbIml + aoff);
            const int boff = (l & 15) * 136 + 32 * ks + 8 * (l >> 4);
            const bf16x8 bh = *(const bf16x8*)(ldsH + boff);
            const bf16x8 bl = *(const bf16x8*)(ldsL + boff);
            gre = MFMA(aRh, bh, gre, 0, 0, 0);
            gre = MFMA(aRh, bl, gre, 0, 0, 0);
            gre = MFMA(aRl, bh, gre, 0, 0, 0);
            gim = MFMA(aIh, bh, gim, 0, 0, 0);
            gim = MFMA(aIh, bl, gim, 0, 0, 0);
            gim = MFMA(aIl, bh, gim, 0, 0, 0);
        }
        float* gre_p = (float*)(ws + OFF_GRE);
        float* gim_p = (float*)(ws + OFF_GIM);
        #pragma unroll
        for (int r = 0; r < 4; ++r) {
            const int n = 16 * w + 4 * (l >> 4) + r;
            gre_p[((size_t)bc3 * N_ + n) * D_ + dq * 16 + (l & 15)] = gre[r];
            gim_p[((size_t)bc3 * N_ + n) * D_ + dq * 16 + (l & 15)] = gim[r];
        }
    }

    // ================= grid barrier =======================================
    grid_barrier((unsigned*)(ws + OFF_BAR), GRID_MAIN);

    // ================= phase B ============================================
    if (bid >= NB_B) return;
    {
        float*   ylds = (float*)smem;                   // [128][33]
        ushortT* Wl   = (ushortT*)(smem + 16896);       // [4][32][72]
        ushortT* uS   = (ushortT*)(smem + 35328);       // [128][32]
        ushortT* kSb  = (ushortT*)(smem + 43520);       // [128][32]

        const int dq = bid & 7, bc = bid >> 3, b = bc >> 2, c = bc & 3;

        // ---- stage uS + kSb (bf16) ---------------------------------------
        {
            const float* ug = u + ((size_t)(b * L_ + c * Q_) * D_) + dq * 32;
            const float* Kg = (const float*)(ws + OFF_KPAD) + dq * 32;
            #pragma unroll
            for (int it = 0; it < 16; ++it) {
                const int idx = t + 256 * it, r = idx >> 5, dl = idx & 31;
                uS[r * 32 + dl] = f2bf(ug[(size_t)r * D_ + dl]);
            }
            #pragma unroll
            for (int it = 0; it < 16; ++it) {
                const int idx = t + 256 * it, r = idx >> 5, dl = idx & 31;
                kSb[r * 32 + dl] = f2bf(Kg[(size_t)r * D_ + dl]);
            }
        }

        // ---- h-combine + W = C*h (skip for c==0) -------------------------
        if (c > 0) {
            const float* gre_p = (const float*)(ws + OFF_GRE);
            const float* gim_p = (const float*)(ws + OFF_GIM);
            #pragma unroll
            for (int r = 0; r < 4; ++r) {
                const int n = 16 * w + 4 * (l >> 4) + r;
                const float eL = expf(Lre[n]);
                const float xr = dt * (-eL * cosf(Lim[n]));
                const float xi = dt * (-eL * sinf(Lim[n]));
                const float er = expf(128.f * xr);
                float sn, cs; sincosf(128.f * xi, &sn, &cs);
                const float qr = er * cs, qi = er * sn;            // a^128
                const float bdr = dt * Bre[n], bdi = dt * Bim[n];
                #pragma unroll
                for (int nt = 0; nt < 2; ++nt) {
                    const int d = dq * 32 + 16 * nt + (l & 15);
                    float hr = 0.f, hi = 0.f, pr = 1.f, pi = 0.f;
                    for (int cp = c - 1; cp >= 0; --cp) {
                        const size_t go = ((size_t)(b * 3 + cp) * N_ + n) * D_ + d;
                        const float gr = gre_p[go], gi = gim_p[go];
                        const float tr = bdr * gr - bdi * gi;
                        const float ti = bdr * gi + bdi * gr;
                        hr += tr * pr - ti * pi;
                        hi += tr * pi + ti * pr;
                        const float npr = pr * qr - pi * qi;
                        const float npi = pr * qi + pi * qr;
                        pr = npr; pi = npi;
                    }
                    const float cr = Pre[n * D_ + d], ci = Pim[n * D_ + d];
                    const float wr = cr * hr - ci * hi;
                    const float wi = cr * hi + ci * hr;
                    const int dl = 16 * nt + (l & 15);
                    ushortT hh, ll;
                    split2(wr, hh, ll);
                    Wl[0 * 2304 + dl * 72 + n] = hh;
                    Wl[1 * 2304 + dl * 72 + n] = ll;
                    split2(wi, hh, ll);
                    Wl[2 * 2304 + dl * 72 + n] = hh;
                    Wl[3 * 2304 + dl * 72 + n] = ll;
                }
            }
        }
        __syncthreads();

        // ---- inter GEMM (or zeros for c==0) ------------------------------
        if (c > 0) {
            const ushortT* P1h = (const ushortT*)(ws + OFF_PT);
            const ushortT* P1l = P1h + 8192;
            const ushortT* P2h = P1h + 16384;
            const ushortT* P2l = P1h + 24576;
            f32x4 yac[2][2] = {};
            #pragma unroll
            for (int ks = 0; ks < 2; ++ks) {
                bf16x8 a1h[2], a1l[2], a2h[2], a2l[2];
                #pragma unroll
                for (int mi = 0; mi < 2; ++mi) {
                    const int aoff = (32 * w + 16 * mi + (l & 15)) * N_ + 32 * ks + 8 * (l >> 4);
                    a1h[mi] = *(const bf16x8*)(P1h + aoff);
                    a1l[mi] = *(const bf16x8*)(P1l + aoff);
                    a2h[mi] = *(const bf16x8*)(P2h + aoff);
                    a2l[mi] = *(const bf16x8*)(P2l + aoff);
                }
                #pragma unroll
                for (int nt = 0; nt < 2; ++nt) {
                    const int boff = (16 * nt + (l & 15)) * 72 + 32 * ks + 8 * (l >> 4);
                    const bf16x8 wrh = *(const bf16x8*)(Wl + 0 * 2304 + boff);
                    const bf16x8 wrl = *(const bf16x8*)(Wl + 1 * 2304 + boff);
                    const bf16x8 wih = *(const bf16x8*)(Wl + 2 * 2304 + boff);
                    const bf16x8 wil = *(const bf16x8*)(Wl + 3 * 2304 + boff);
                    #pragma unroll
                    for (int mi = 0; mi < 2; ++mi) {
                        yac[mi][nt] = MFMA(a1h[mi], wrh, yac[mi][nt], 0, 0, 0);
                        yac[mi][nt] = MFMA(a1h[mi], wrl, yac[mi][nt], 0, 0, 0);
                        yac[mi][nt] = MFMA(a1l[mi], wrh, yac[mi][nt], 0, 0, 0);
                        yac[mi][nt] = MFMA(a2h[mi], wih, yac[mi][nt], 0, 0, 0);
                        yac[mi][nt] = MFMA(a2h[mi], wil, yac[mi][nt], 0, 0, 0);
                        yac[mi][nt] = MFMA(a2l[mi], wih, yac[mi][nt], 0, 0, 0);
                    }
                }
            }
            #pragma unroll
            for (int mi = 0; mi < 2; ++mi)
                #pragma unroll
                for (int nt = 0; nt < 2; ++nt)
                    #pragma unroll
                    for (int r = 0; r < 4; ++r)
                        ylds[(32 * w + 16 * mi + 4 * (l >> 4) + r) * 33
                             + 16 * nt + (l & 15)] = yac[mi][nt][r];
        } else {
            #pragma unroll
            for (int it = 0; it < 16; ++it) {
                const int idx = t + 256 * it;
                ylds[(idx >> 5) * 33 + (idx & 31)] = 0.f;
            }
        }
        __syncthreads();

        // ---- intra FIR (LDS) + add + store -------------------------------
        const int d = t & 31, ig = t >> 5, i0 = 16 * ig;
        float* yb = y + ((size_t)(b * L_ + c * Q_ + i0)) * D_ + dq * 32 + d;

        float W16[16];
        W16[0] = 0.f;
        #pragma unroll
        for (int r = 1; r < 16; ++r) W16[r] = bf2f(kSb[(i0 + r) * 32 + d]);
        float acc[16];
        #pragma unroll
        for (int r = 0; r < 16; ++r) acc[r] = 0.f;

        for (int j0 = 0; j0 <= i0; j0 += 16) {
            #pragma unroll
            for (int m = 0; m < 16; ++m) {       // j = j0+m
                const int j = j0 + m;
                const float uv = bf2f(uS[j * 32 + d]);
                const float kv = bf2f(kSb[(i0 - j) * 32 + d]);
                acc[0] = fmaf(kv, uv, acc[0]);
                #pragma unroll
                for (int r = 1; r < 16; ++r)
                    acc[r] = fmaf(W16[(r - m) & 15], uv, acc[r]);
                W16[(16 - m) & 15] = kv;
            }
        }
        #pragma unroll
        for (int ii = 0; ii < 16; ++ii)
            yb[ii * D_] = acc[ii] + ylds[(i0 + ii) * 33 + d];
    }
}

extern "C" void kernel_launch(void* const* d_in, const int* in_sizes, int n_in,
                              void* d_out, int out_size, void* d_ws, size_t ws_size,
                              hipStream_t stream) {
    const float* u     = (const float*)d_in[0];
    const float* Lre   = (const float*)d_in[1];
    const float* Lim   = (const float*)d_in[2];
    const float* Bre   = (const float*)d_in[3];
    const float* Bim   = (const float*)d_in[4];
    const float* Pre   = (const float*)d_in[5];
    const float* Pim   = (const float*)d_in[6];
    const float* logdt = (const float*)d_in[7];
    float* y = (float*)d_out;
    char* ws = (char*)d_ws;       // ~6.6 MB used

    prep_kernel<<<137, 256, 0, stream>>>(Lre, Lim, Bre, Bim, Pre, Pim, logdt, ws);
    main_kernel<<<GRID_MAIN, 256, 0, stream>>>(u, Lre, Lim, Bre, Bim,
                                               Pre, Pim, logdt, ws, y);
}

// Round 14
// 47.363 us; speedup vs baseline: 2.4488x; 2.4488x over previous
//
#include <hip/hip_runtime.h>

#define BATCH  16
#define LEN    512
#define NSTATE 64
#define DMODEL 256
#define WAVES  4       // 4 adjacent d per block -> L2-merged y writes

// single-instruction DPP adds (dst = dpp(src) + src).
// s_nop 1 = 2 wait states: required because a DPP op reading a VGPR written
// by a preceding VALU op needs 2 manually-inserted wait states (inline asm
// bypasses the compiler's automatic hazard insertion -> r13's failure).
__device__ __forceinline__ float dpp_add_xor1(float x) {
    float o;
    asm("s_nop 1\n\t"
        "v_add_f32_dpp %0, %1, %1 quad_perm:[1,0,3,2] row_mask:0xf bank_mask:0xf"
        : "=v"(o) : "v"(x));
    return o;
}
__device__ __forceinline__ float dpp_add_xor2(float x) {
    float o;
    asm("s_nop 1\n\t"
        "v_add_f32_dpp %0, %1, %1 quad_perm:[2,3,0,1] row_mask:0xf bank_mask:0xf"
        : "=v"(o) : "v"(x));
    return o;
}
__device__ __forceinline__ float dpp_add_halfmirror(float x) {
    float o;
    asm("s_nop 1\n\t"
        "v_add_f32_dpp %0, %1, %1 row_half_mirror row_mask:0xf bank_mask:0xf"
        : "=v"(o) : "v"(x));
    return o;
}

__global__ __launch_bounds__(WAVES * 64, 4)
void s4d_scan_kernel(const float* __restrict__ u,
                     const float* __restrict__ Lre_p, const float* __restrict__ Lim_p,
                     const float* __restrict__ Bre_p, const float* __restrict__ Bim_p,
                     const float* __restrict__ Pre_p, const float* __restrict__ Pim_p,
                     const float* __restrict__ logdt_p,
                     float* __restrict__ y)
{
    // wave-private 8 x 32 group-sum slab; row stride 36 floats:
    //  - b128 writes (8 lanes, addr 144g+16*s4): banks 4(g+s4)%32 -> conflict-free
    //  - b32 reads (addr (36g+tl)*4): 2-way -> free
    __shared__ float red[WAVES][8][36];          // 4.6 KB

    const int tid  = threadIdx.x;
    const int lane = tid & 63;
    const int widx = tid >> 6;
    const int wid  = blockIdx.x * WAVES + widx;  // 0..4095
    const int b    = wid >> 8;                   // / DMODEL
    const int d    = wid & 255;                  // % DMODEL

    // ---- per-lane (state n = lane) coefficients --------------------------
    const float dt  = expf(logdt_p[0]);
    const float Lre = Lre_p[lane];
    const float Lim = Lim_p[lane];
    const float eL  = expf(Lre);
    const float wre = -eL * cosf(Lim);           // w = -exp(Lambda)
    const float wim = -eL * sinf(Lim);
    const float mag = expf(dt * wre);            // a = exp(dt*w)
    const float are = mag * cosf(dt * wim);
    const float aim = mag * sinf(dt * wim);
    const float Bdre = dt * Bre_p[lane];
    const float Bdim = dt * Bim_p[lane];
    const float Pre  = Pre_p[lane * DMODEL + d];
    const float Pim  = Pim_p[lane * DMODEL + d];
    const float Gre = Pre * Bdre - Pim * Bdim;   // G = C*Bd (fold projection)
    const float Gim = Pre * Bdim + Pim * Bdre;

    float zre = 0.f, zim = 0.f;                  // z = C*x per state

    const float* up = u + (size_t)b * LEN * DMODEL + d;   // + t*DMODEL
    float*       yp = y + (size_t)b * LEN * DMODEL + d;

    const int tl = lane & 31;                    // output slot in reduce phase
    const int h  = lane >> 5;                    // group-half this lane sums
    float* const myred = &red[widx][0][0];
    float* const wrp   = &red[widx][lane >> 3][0];   // this lane's group row

    // prefetch macro-batch 0: 64 timesteps, one per lane
    float ucur = up[lane * DMODEL];

    for (int m = 0; m < LEN / 64; ++m) {
        // issue next macro-batch load now (wrap on last iter; values unused)
        const int mn = (m + 1) & (LEN / 64 - 1);
        float unext = up[(mn * 64 + lane) * DMODEL];

        #pragma unroll
        for (int half = 0; half < 2; ++half) {
            // ---- 32 steps; per 4 steps one b128 write of 8-lane group sums
            #pragma unroll
            for (int s4 = 0; s4 < 8; ++s4) {
                float4 pack;
                #pragma unroll
                for (int k = 0; k < 4; ++k) {
                    const int tau = s4 * 4 + k;
                    const float us = __uint_as_float(
                        __builtin_amdgcn_readlane(__float_as_uint(ucur),
                                                  half * 32 + tau));
                    // z = a*z + G*u   (6 VALU)
                    const float nzre = fmaf(are, zre, fmaf(-aim, zim, Gre * us));
                    const float nzim = fmaf(are, zim, fmaf( aim, zre, Gim * us));
                    zre = nzre;
                    zim = nzim;
                    // 8-lane group sum of zre (3 DPP adds on the VALU pipe)
                    float s = dpp_add_xor1(zre);
                    s = dpp_add_xor2(s);
                    s = dpp_add_halfmirror(s);
                    ((float*)&pack)[k] = s;
                }
                if ((lane & 7) == 0)
                    *(float4*)(wrp + s4 * 4) = pack;   // ds_write_b128
            }

            // ---- transpose-reduce 8 groups (wave-private, no barrier) ----
            float s0 = myred[(4 * h + 0) * 36 + tl];
            float s1 = myred[(4 * h + 1) * 36 + tl];
            float s2 = myred[(4 * h + 2) * 36 + tl];
            float s3 = myred[(4 * h + 3) * 36 + tl];
            float s = (s0 + s1) + (s2 + s3);
            s += __shfl_xor(s, 32, 64);          // combine the two halves
            if (lane < 32)
                yp[(m * 64 + half * 32 + tl) * DMODEL] = s;
        }
        ucur = unext;
    }
}

extern "C" void kernel_launch(void* const* d_in, const int* in_sizes, int n_in,
                              void* d_out, int out_size, void* d_ws, size_t ws_size,
                              hipStream_t stream) {
    const float* u      = (const float*)d_in[0];
    const float* Lre    = (const float*)d_in[1];
    const float* Lim    = (const float*)d_in[2];
    const float* Bre    = (const float*)d_in[3];
    const float* Bim    = (const float*)d_in[4];
    const float* Pre    = (const float*)d_in[5];
    const float* Pim    = (const float*)d_in[6];
    const float* logdt  = (const float*)d_in[7];
    float* y = (float*)d_out;

    const int nblocks = (BATCH * DMODEL) / WAVES;   // 1024
    s4d_scan_kernel<<<nblocks, WAVES * 64, 0, stream>>>(
        u, Lre, Lim, Bre, Bim, Pre, Pim, logdt, y);
}